// Round 1
// baseline (5847.111 us; speedup 1.0000x reference)
//
#include <hip/hip_runtime.h>
#include <hip/hip_bf16.h>
#include <cstdint>

#define B_ 8
#define T_ 2048
#define C_ 2048
#define A_ 2048
#define H_ 32
#define BT_ (B_*T_)

typedef short short8 __attribute__((ext_vector_type(8)));
typedef float floatx4 __attribute__((ext_vector_type(4)));

__device__ __forceinline__ unsigned short f2bf(float f) {
  union { float f; uint32_t u; } a; a.f = f;
  uint32_t r = a.u + 0x7fffu + ((a.u >> 16) & 1u);   // RNE
  return (unsigned short)(r >> 16);
}
__device__ __forceinline__ float bf2f(unsigned short s) {
  union { uint32_t u; float f; } a; a.u = ((uint32_t)s) << 16;
  return a.f;
}

// ---------------- weight prep: hi/lo bf16 split ----------------
__global__ void conv_hilo(const float* __restrict__ s, unsigned short* __restrict__ hi,
                          unsigned short* __restrict__ lo, int n) {
  int i = blockIdx.x * 256 + threadIdx.x;
  if (i < n) {
    float v = s[i];
    unsigned short h = f2bf(v);
    hi[i] = h;
    lo[i] = f2bf(v - bf2f(h));
  }
}

// src (2048 x NV) f32 -> dst (NP x 2048) bf16, rows >= NV zero-padded
__global__ void transpose_pad(const float* __restrict__ s, unsigned short* __restrict__ d, int NP, int NV) {
  int i = blockIdx.x * 256 + threadIdx.x;  // over NP*2048
  int n = i >> 11, kk = i & 2047;
  if (n < NP) d[i] = (n < NV) ? f2bf(s[kk * NV + n]) : (unsigned short)0;
}

// ---------------- token shift + maa_x mix: xxx = x + (shift(x)-x)*time_maa_x (bf16) ----------------
__global__ void shift_mix(const float* __restrict__ x, const float* __restrict__ tmx,
                          unsigned short* __restrict__ xxx) {
  size_t i4 = (size_t)blockIdx.x * 256 + threadIdx.x;   // over BT*C/4
  size_t i = i4 * 4;
  int c = (int)(i & 2047);
  int t = (int)((i >> 11) & 2047);
  float4 xv = *(const float4*)&x[i];
  float4 pv = make_float4(0.f, 0.f, 0.f, 0.f);
  if (t > 0) pv = *(const float4*)&x[i - 2048];
  float4 tv = *(const float4*)&tmx[c];
  ushort4 m;
  m.x = f2bf(xv.x + (pv.x - xv.x) * tv.x);
  m.y = f2bf(xv.y + (pv.y - xv.y) * tv.y);
  m.z = f2bf(xv.z + (pv.z - xv.z) * tv.z);
  m.w = f2bf(xv.w + (pv.w - xv.w) * tv.w);
  *(ushort4*)&xxx[i] = m;
}

// ---------------- async global->LDS helper ----------------
__device__ __forceinline__ void gll16(const void* g, void* l) {
  __builtin_amdgcn_global_load_lds(
      (const __attribute__((address_space(1))) void*)g,
      (__attribute__((address_space(3))) void*)l, 16, 0, 0);
}

// ---------------- plain bf16 GEMM (small-N lora paths): C = A * B^T ----------------
// EPI: 2 = tanh->f32
template<int EPI>
__global__ __launch_bounds__(256)
void gemm_bt(const unsigned short* __restrict__ Am, const unsigned short* __restrict__ Bm,
             void* __restrict__ Cp, int M, int N, int K) {
  __shared__ unsigned short As[128 * 32];
  __shared__ unsigned short Bs[128 * 32];
  const int tid = threadIdx.x;
  const int wid = tid >> 6, lane = tid & 63;
  const int quad = lane >> 4, l15 = lane & 15;
  const long bm = (long)blockIdx.x * 128, bn = (long)blockIdx.y * 128;
  const int wm = (wid & 1) * 64, wn = (wid >> 1) * 64;

  floatx4 acc[4][4];
#pragma unroll
  for (int a = 0; a < 4; a++)
#pragma unroll
    for (int b = 0; b < 4; b++) { floatx4 z = {0.f, 0.f, 0.f, 0.f}; acc[a][b] = z; }

  const int stg_row = wid * 32 + (lane >> 2);
  const int stg_k   = (lane & 3) * 8;
  const int stg_lds = wid * 1024 + lane * 8;

  for (int k0 = 0; k0 < K; k0 += 32) {
    __syncthreads();
#pragma unroll
    for (int p = 0; p < 2; ++p) {
      gll16(Am + (bm + stg_row + p * 16) * (long)K + k0 + stg_k, &As[stg_lds + p * 512]);
      gll16(Bm + (bn + stg_row + p * 16) * (long)K + k0 + stg_k, &Bs[stg_lds + p * 512]);
    }
    __syncthreads();

    short8 af[4], bfr[4];
#pragma unroll
    for (int mi = 0; mi < 4; mi++) af[mi] = *(const short8*)&As[(wm + mi * 16 + l15) * 32 + quad * 8];
#pragma unroll
    for (int ni = 0; ni < 4; ni++) bfr[ni] = *(const short8*)&Bs[(wn + ni * 16 + l15) * 32 + quad * 8];
#pragma unroll
    for (int mi = 0; mi < 4; mi++)
#pragma unroll
      for (int ni = 0; ni < 4; ni++)
        acc[mi][ni] = __builtin_amdgcn_mfma_f32_16x16x32_bf16(af[mi], bfr[ni], acc[mi][ni], 0, 0, 0);
  }

#pragma unroll
  for (int mi = 0; mi < 4; mi++)
#pragma unroll
    for (int ni = 0; ni < 4; ni++)
#pragma unroll
      for (int vv = 0; vv < 4; ++vv) {
        long row = bm + wm + mi * 16 + quad * 4 + vv;
        long col = bn + wn + ni * 16 + l15;
        float val = acc[mi][ni][vv];
        if (EPI == 2) ((float*)Cp)[row * N + col] = tanhf(val);
      }
}

// ---------------- split-B GEMM: C = A * (Bh+Bl)^T  (weight-exact) ----------------
// EPI: 0 = ->bf16, 1 = silu->bf16, 3 = ->f32
template<int EPI>
__global__ __launch_bounds__(256)
void gemm_sb(const unsigned short* __restrict__ Am, const unsigned short* __restrict__ Bhm,
             const unsigned short* __restrict__ Blm, void* __restrict__ Cp, int M, int N, int K) {
  __shared__ unsigned short As[128 * 32];
  __shared__ unsigned short Bhs[128 * 32];
  __shared__ unsigned short Bls[128 * 32];
  const int tid = threadIdx.x;
  const int wid = tid >> 6, lane = tid & 63;
  const int quad = lane >> 4, l15 = lane & 15;
  const long bm = (long)blockIdx.x * 128, bn = (long)blockIdx.y * 128;
  const int wm = (wid & 1) * 64, wn = (wid >> 1) * 64;

  floatx4 acc[4][4];
#pragma unroll
  for (int a = 0; a < 4; a++)
#pragma unroll
    for (int b = 0; b < 4; b++) { floatx4 z = {0.f, 0.f, 0.f, 0.f}; acc[a][b] = z; }

  const int stg_row = wid * 32 + (lane >> 2);
  const int stg_k   = (lane & 3) * 8;
  const int stg_lds = wid * 1024 + lane * 8;

  for (int k0 = 0; k0 < K; k0 += 32) {
    __syncthreads();
#pragma unroll
    for (int p = 0; p < 2; ++p) {
      const long rowA = (bm + stg_row + p * 16) * (long)K + k0 + stg_k;
      const long rowB = (bn + stg_row + p * 16) * (long)K + k0 + stg_k;
      gll16(Am  + rowA, &As [stg_lds + p * 512]);
      gll16(Bhm + rowB, &Bhs[stg_lds + p * 512]);
      gll16(Blm + rowB, &Bls[stg_lds + p * 512]);
    }
    __syncthreads();

    short8 af[4], bh[4], bl[4];
#pragma unroll
    for (int mi = 0; mi < 4; mi++) af[mi] = *(const short8*)&As[(wm + mi * 16 + l15) * 32 + quad * 8];
#pragma unroll
    for (int ni = 0; ni < 4; ni++) {
      bh[ni] = *(const short8*)&Bhs[(wn + ni * 16 + l15) * 32 + quad * 8];
      bl[ni] = *(const short8*)&Bls[(wn + ni * 16 + l15) * 32 + quad * 8];
    }
#pragma unroll
    for (int mi = 0; mi < 4; mi++)
#pragma unroll
      for (int ni = 0; ni < 4; ni++) {
        acc[mi][ni] = __builtin_amdgcn_mfma_f32_16x16x32_bf16(af[mi], bh[ni], acc[mi][ni], 0, 0, 0);
        acc[mi][ni] = __builtin_amdgcn_mfma_f32_16x16x32_bf16(af[mi], bl[ni], acc[mi][ni], 0, 0, 0);
      }
  }

#pragma unroll
  for (int mi = 0; mi < 4; mi++)
#pragma unroll
    for (int ni = 0; ni < 4; ni++)
#pragma unroll
      for (int vv = 0; vv < 4; ++vv) {
        long row = bm + wm + mi * 16 + quad * 4 + vv;
        long col = bn + wn + ni * 16 + l15;
        float val = acc[mi][ni][vv];
        if (EPI == 0) {
          ((unsigned short*)Cp)[row * N + col] = f2bf(val);
        } else if (EPI == 1) {
          float s = val / (1.f + __expf(-val));
          ((unsigned short*)Cp)[row * N + col] = f2bf(s);
        } else {
          ((float*)Cp)[row * N + col] = val;
        }
      }
}

// ---------------- 3-term GEMM: C = Ah*Bh^T + Ah*Bl^T + Al*Bh^T -> f32 (final proj) ----------------
__global__ __launch_bounds__(256)
void gemm_s3(const unsigned short* __restrict__ Ahm, const unsigned short* __restrict__ Alm,
             const unsigned short* __restrict__ Bhm, const unsigned short* __restrict__ Blm,
             float* __restrict__ Cp, int M, int N, int K) {
  __shared__ unsigned short Ahs[128 * 32];
  __shared__ unsigned short Als[128 * 32];
  __shared__ unsigned short Bhs[128 * 32];
  __shared__ unsigned short Bls[128 * 32];
  const int tid = threadIdx.x;
  const int wid = tid >> 6, lane = tid & 63;
  const int quad = lane >> 4, l15 = lane & 15;
  const long bm = (long)blockIdx.x * 128, bn = (long)blockIdx.y * 128;
  const int wm = (wid & 1) * 64, wn = (wid >> 1) * 64;

  floatx4 acc[4][4];
#pragma unroll
  for (int a = 0; a < 4; a++)
#pragma unroll
    for (int b = 0; b < 4; b++) { floatx4 z = {0.f, 0.f, 0.f, 0.f}; acc[a][b] = z; }

  const int stg_row = wid * 32 + (lane >> 2);
  const int stg_k   = (lane & 3) * 8;
  const int stg_lds = wid * 1024 + lane * 8;

  for (int k0 = 0; k0 < K; k0 += 32) {
    __syncthreads();
#pragma unroll
    for (int p = 0; p < 2; ++p) {
      const long rowA = (bm + stg_row + p * 16) * (long)K + k0 + stg_k;
      const long rowB = (bn + stg_row + p * 16) * (long)K + k0 + stg_k;
      gll16(Ahm + rowA, &Ahs[stg_lds + p * 512]);
      gll16(Alm + rowA, &Als[stg_lds + p * 512]);
      gll16(Bhm + rowB, &Bhs[stg_lds + p * 512]);
      gll16(Blm + rowB, &Bls[stg_lds + p * 512]);
    }
    __syncthreads();

    short8 ah[4], al[4], bh[4], bl[4];
#pragma unroll
    for (int mi = 0; mi < 4; mi++) {
      ah[mi] = *(const short8*)&Ahs[(wm + mi * 16 + l15) * 32 + quad * 8];
      al[mi] = *(const short8*)&Als[(wm + mi * 16 + l15) * 32 + quad * 8];
    }
#pragma unroll
    for (int ni = 0; ni < 4; ni++) {
      bh[ni] = *(const short8*)&Bhs[(wn + ni * 16 + l15) * 32 + quad * 8];
      bl[ni] = *(const short8*)&Bls[(wn + ni * 16 + l15) * 32 + quad * 8];
    }
#pragma unroll
    for (int mi = 0; mi < 4; mi++)
#pragma unroll
      for (int ni = 0; ni < 4; ni++) {
        acc[mi][ni] = __builtin_amdgcn_mfma_f32_16x16x32_bf16(ah[mi], bh[ni], acc[mi][ni], 0, 0, 0);
        acc[mi][ni] = __builtin_amdgcn_mfma_f32_16x16x32_bf16(ah[mi], bl[ni], acc[mi][ni], 0, 0, 0);
        acc[mi][ni] = __builtin_amdgcn_mfma_f32_16x16x32_bf16(al[mi], bh[ni], acc[mi][ni], 0, 0, 0);
      }
  }

#pragma unroll
  for (int mi = 0; mi < 4; mi++)
#pragma unroll
    for (int ni = 0; ni < 4; ni++)
#pragma unroll
      for (int vv = 0; vv < 4; ++vv) {
        long row = bm + wm + mi * 16 + quad * 4 + vv;
        long col = bn + wn + ni * 16 + l15;
        Cp[row * N + col] = acc[mi][ni][vv];
      }
}

// ---------------- fused LoRA-mix (xx recomputed inline) ----------------
__global__ __launch_bounds__(256)
void mix_lora(const float* __restrict__ x,
              const float* __restrict__ m5, const float* __restrict__ w2,
              const float* __restrict__ tmw, const float* __restrict__ tmk,
              const float* __restrict__ tmv, const float* __restrict__ tmr,
              const float* __restrict__ tmg,
              unsigned short* __restrict__ xw, unsigned short* __restrict__ xk,
              unsigned short* __restrict__ xv, unsigned short* __restrict__ xr,
              unsigned short* __restrict__ xg) {
  const int bt0 = blockIdx.x * 16;
  const int tid = threadIdx.x;
  const float* tms[5] = {tmw, tmk, tmv, tmr, tmg};
  unsigned short* outs[5] = {xw, xk, xv, xr, xg};
  for (int cc = 0; cc < 8; ++cc) {
    const int c = cc * 256 + tid;
    float xv_[16], xxv_[16];
#pragma unroll
    for (int b = 0; b < 16; b++) {
      const int bt = bt0 + b;
      size_t idx = ((size_t)bt << 11) + c;
      float xc = x[idx];
      float xp = ((bt & 2047) > 0) ? x[idx - 2048] : 0.f;
      xv_[b] = xc; xxv_[b] = xp - xc;
    }
#pragma unroll
    for (int f = 0; f < 5; ++f) {
      const float tmf = tms[f][c];
      float acc[16];
#pragma unroll
      for (int b = 0; b < 16; b++) acc[b] = 0.f;
      for (int dc = 0; dc < 8; ++dc) {
        float wv0 = w2[((size_t)(f * 32 + dc * 4 + 0) << 11) + c];
        float wv1 = w2[((size_t)(f * 32 + dc * 4 + 1) << 11) + c];
        float wv2 = w2[((size_t)(f * 32 + dc * 4 + 2) << 11) + c];
        float wv3 = w2[((size_t)(f * 32 + dc * 4 + 3) << 11) + c];
#pragma unroll
        for (int b = 0; b < 16; b++) {
          float4 mv = *(const float4*)&m5[((size_t)(bt0 + b) << 8) + f * 32 + dc * 4];
          acc[b] += mv.x * wv0 + mv.y * wv1 + mv.z * wv2 + mv.w * wv3;
        }
      }
#pragma unroll
      for (int b = 0; b < 16; b++) {
        size_t idx = ((size_t)(bt0 + b) << 11) + c;
        outs[f][idx] = f2bf(xv_[b] + xxv_[b] * (tmf + acc[b]));
      }
    }
  }
}

// ---------------- decay: dec = exp(-exp(td + t1 @ decay_w2)) (f32) ----------------
__global__ __launch_bounds__(256)
void decay_kernel(const float* __restrict__ t1, const float* __restrict__ w2d,
                  const float* __restrict__ td, float* __restrict__ dec) {
  const int bt0 = blockIdx.x * 16;
  const int tid = threadIdx.x;
  for (int cc = 0; cc < 8; ++cc) {
    const int a = cc * 256 + tid;
    const float tda = td[a];
    float acc[16];
#pragma unroll
    for (int b = 0; b < 16; b++) acc[b] = 0.f;
    for (int dc = 0; dc < 16; ++dc) {
      float wv0 = w2d[((size_t)(dc * 4 + 0) << 11) + a];
      float wv1 = w2d[((size_t)(dc * 4 + 1) << 11) + a];
      float wv2 = w2d[((size_t)(dc * 4 + 2) << 11) + a];
      float wv3 = w2d[((size_t)(dc * 4 + 3) << 11) + a];
#pragma unroll
      for (int b = 0; b < 16; b++) {
        float4 mv = *(const float4*)&t1[((size_t)(bt0 + b) << 7) + dc * 4];
        acc[b] += mv.x * wv0 + mv.y * wv1 + mv.z * wv2 + mv.w * wv3;
      }
    }
#pragma unroll
    for (int b = 0; b < 16; b++) {
      dec[((size_t)(bt0 + b) << 11) + a] = __expf(-__expf(tda + acc[b]));
    }
  }
}

// ---------------- WKV6 scan + fused GroupNorm*g epilogue (pipelined) ----------------
// block = one (b,h); wave w owns channels [16w,16w+16), lane j = state column.
// v2: register prefetch 2 iterations (4 timesteps) deep; raw s_barrier with
// lgkmcnt-only wait (prefetched global loads stay in flight across barriers);
// 1 barrier per 2 timesteps via double-buffered ypart; w0 GroupNorm epilogue
// overlaps other waves' next-iteration compute.
// Overlay safety: z writes touch rows <= t+1 (max 1-iter wave skew); prefetch
// reads rows t+4..t+5 -> disjoint. Same column-ownership argument as v1.
template<int KF32>
__global__ __launch_bounds__(256, 1)
void wkv6_fused(const unsigned short* __restrict__ r, const unsigned short* __restrict__ k16,
                const float* __restrict__ k32, const float* __restrict__ v,
                const float* __restrict__ dec, const float* __restrict__ u,
                unsigned short* __restrict__ g_zhi, unsigned short* __restrict__ zlo,
                const float* __restrict__ lnw, const float* __restrict__ lnb) {
  const int bh = blockIdx.x;
  const int b = bh >> 5, h = bh & 31;
  const int tid = threadIdx.x;
  const int w = __builtin_amdgcn_readfirstlane(tid >> 6);
  const int j = tid & 63;
  __shared__ float ypart[2][2][4][64];   // [pingpong][substep][wave][col]
  float S[16];
#pragma unroll
  for (int ii = 0; ii < 16; ii++) S[ii] = 0.f;
  float uu[16];
#pragma unroll
  for (int ii = 0; ii < 16; ii++) uu[ii] = u[h * 64 + w * 16 + ii];
  const float la = lnw[h * 64 + j], lb = lnb[h * 64 + j];
  const size_t base = ((size_t)b * T_) * (size_t)A_ + h * 64;
  const int cw = w * 16;
  const int NIT = T_ / 2;                // iterations of 2 timesteps each

// issue global loads for iteration IT (2 timesteps) into a named register buffer
#define WKV_ISSUE(BR, BD, BKF, BKH, BV, BG, IT) do {                              \
    const int it_ = (IT);                                                         \
    if (it_ < NIT) {                                                              \
      _Pragma("unroll")                                                           \
      for (int s = 0; s < 2; ++s) {                                               \
        const size_t o_ = base + (size_t)(it_ * 2 + s) * A_;                      \
        _Pragma("unroll")                                                         \
        for (int dc = 0; dc < 4; ++dc) {                                          \
          BR[s][dc] = *(const ushort4*)&r[o_ + cw + dc * 4];                      \
          BD[s][dc] = *(const float4*)&dec[o_ + cw + dc * 4];                     \
          if (KF32) BKF[s][dc] = *(const float4*)&k32[o_ + cw + dc * 4];          \
          else      BKH[s][dc] = *(const ushort4*)&k16[o_ + cw + dc * 4];         \
        }                                                                         \
        BV[s] = v[o_ + j];                                                        \
        BG[s] = g_zhi[o_ + j];                                                    \
      }                                                                           \
    }                                                                             \
  } while (0)

// consume buffer for iteration IT, reissue it for IT+2, compute, sync, epilogue
#define WKV_HALF(BR, BD, BKF, BKH, BV, BG, IT, IB) do {                           \
    float rr_[2][16], kk_[2][16], dd_[2][16];                                     \
    float vj_[2]; unsigned short gg_[2];                                          \
    _Pragma("unroll")                                                             \
    for (int s = 0; s < 2; ++s) {                                                 \
      _Pragma("unroll")                                                           \
      for (int dc = 0; dc < 4; ++dc) {                                            \
        rr_[s][dc*4+0] = bf2f(BR[s][dc].x); rr_[s][dc*4+1] = bf2f(BR[s][dc].y);   \
        rr_[s][dc*4+2] = bf2f(BR[s][dc].z); rr_[s][dc*4+3] = bf2f(BR[s][dc].w);   \
        dd_[s][dc*4+0] = BD[s][dc].x; dd_[s][dc*4+1] = BD[s][dc].y;               \
        dd_[s][dc*4+2] = BD[s][dc].z; dd_[s][dc*4+3] = BD[s][dc].w;               \
        if (KF32) {                                                               \
          kk_[s][dc*4+0] = BKF[s][dc].x; kk_[s][dc*4+1] = BKF[s][dc].y;           \
          kk_[s][dc*4+2] = BKF[s][dc].z; kk_[s][dc*4+3] = BKF[s][dc].w;           \
        } else {                                                                  \
          kk_[s][dc*4+0] = bf2f(BKH[s][dc].x); kk_[s][dc*4+1] = bf2f(BKH[s][dc].y); \
          kk_[s][dc*4+2] = bf2f(BKH[s][dc].z); kk_[s][dc*4+3] = bf2f(BKH[s][dc].w); \
        }                                                                         \
      }                                                                           \
      vj_[s] = BV[s]; gg_[s] = BG[s];                                             \
    }                                                                             \
    WKV_ISSUE(BR, BD, BKF, BKH, BV, BG, (IT) + 2);                                \
    float yac0, yac1;                                                             \
    {                                                                             \
      float ya = 0.f;                                                             \
      _Pragma("unroll")                                                           \
      for (int ii = 0; ii < 16; ii++) {                                           \
        float kv = kk_[0][ii] * vj_[0];                                           \
        ya = fmaf(rr_[0][ii], fmaf(uu[ii], kv, S[ii]), ya);                       \
        S[ii] = fmaf(dd_[0][ii], S[ii], kv);                                      \
      }                                                                           \
      yac0 = ya;                                                                  \
      ya = 0.f;                                                                   \
      _Pragma("unroll")                                                           \
      for (int ii = 0; ii < 16; ii++) {                                           \
        float kv = kk_[1][ii] * vj_[1];                                           \
        ya = fmaf(rr_[1][ii], fmaf(uu[ii], kv, S[ii]), ya);                       \
        S[ii] = fmaf(dd_[1][ii], S[ii], kv);                                      \
      }                                                                           \
      yac1 = ya;                                                                  \
    }                                                                             \
    ypart[IB][0][w][j] = yac0;                                                    \
    ypart[IB][1][w][j] = yac1;                                                    \
    asm volatile("s_waitcnt lgkmcnt(0)\n\ts_barrier" ::: "memory");               \
    if (w == 0) {                                                                 \
      const size_t oz0 = base + (size_t)((IT) * 2) * A_ + j;                      \
      _Pragma("unroll")                                                           \
      for (int s = 0; s < 2; ++s) {                                               \
        float yj = ypart[IB][s][0][j] + ypart[IB][s][1][j]                        \
                 + ypart[IB][s][2][j] + ypart[IB][s][3][j];                       \
        float sm = yj, sq = yj * yj;                                              \
        _Pragma("unroll")                                                         \
        for (int d = 32; d > 0; d >>= 1) {                                        \
          sm += __shfl_xor(sm, d, 64); sq += __shfl_xor(sq, d, 64);               \
        }                                                                         \
        float mu = sm * (1.f / 64.f);                                             \
        float var = sq * (1.f / 64.f) - mu * mu;                                  \
        float rs = rsqrtf(var + 6.4e-4f);   /* EPS = 1e-5 * 64 */                 \
        float yn = (yj - mu) * rs * la + lb;                                      \
        float z = yn * bf2f(gg_[s]);                                              \
        unsigned short zh = f2bf(z);                                              \
        size_t oz = oz0 + (size_t)s * A_;                                         \
        g_zhi[oz] = zh;                                                           \
        zlo[oz] = f2bf(z - bf2f(zh));                                             \
      }                                                                           \
    }                                                                             \
  } while (0)

  // ping-pong prefetch buffers (all statically indexed)
  ushort4 Pr[2][4]; float4 Pd[2][4]; float4 Pkf[2][4]; ushort4 Pkh[2][4];
  float Pv[2]; unsigned short Pg[2];
  ushort4 Qr[2][4]; float4 Qd[2][4]; float4 Qkf[2][4]; ushort4 Qkh[2][4];
  float Qv[2]; unsigned short Qg[2];

  WKV_ISSUE(Pr, Pd, Pkf, Pkh, Pv, Pg, 0);
  WKV_ISSUE(Qr, Qd, Qkf, Qkh, Qv, Qg, 1);

  for (int i = 0; i < NIT; i += 2) {
    WKV_HALF(Pr, Pd, Pkf, Pkh, Pv, Pg, i,     0);
    WKV_HALF(Qr, Qd, Qkf, Qkh, Qv, Qg, i + 1, 1);
  }
#undef WKV_ISSUE
#undef WKV_HALF
}

// ---------------- launch ----------------
extern "C" void kernel_launch(void* const* d_in, const int* in_sizes, int n_in,
                              void* d_out, int out_size, void* d_ws, size_t ws_size,
                              hipStream_t stream) {
  (void)in_sizes; (void)n_in; (void)out_size;
  const float* x   = (const float*)d_in[0];
  const float* tmx = (const float*)d_in[1];
  const float* tmw = (const float*)d_in[2];
  const float* tmk = (const float*)d_in[3];
  const float* tmv = (const float*)d_in[4];
  const float* tmr = (const float*)d_in[5];
  const float* tmg = (const float*)d_in[6];
  const float* w1  = (const float*)d_in[7];   // (C,160)
  const float* w2  = (const float*)d_in[8];   // (5,32,C)
  const float* td  = (const float*)d_in[9];   // (A)
  const float* dw1 = (const float*)d_in[10];  // (C,64)
  const float* dw2 = (const float*)d_in[11];  // (64,A)
  const float* u   = (const float*)d_in[12];  // (H,N)
  const float* Wr  = (const float*)d_in[13];
  const float* Wk  = (const float*)d_in[14];
  const float* Wv  = (const float*)d_in[15];
  const float* Wg  = (const float*)d_in[16];
  const float* Wo  = (const float*)d_in[17];
  const float* lnw = (const float*)d_in[18];
  const float* lnb = (const float*)d_in[19];

  char* ws = (char*)d_ws;
  const size_t MB = 1024 * 1024;
  // 472MB layout (proven safe footprint), lifetime-overlapped:
  // [0,64)    U0: xxx -> g -> z_hi (in place)
  // [64,80)       m5 (f32, 16MB) -> later v-f32 lower half spans [64,128)
  // [128,192) U2: bxk (w1T scratch at [128,129) pre-mix) -> v-f32 upper half
  // [192,256) U3: bxv -> dec lower half
  // [256,320) U4: bxw -> dec upper half     (dec = [192,320) f32)
  // [320,384) U5: bxg -> r -> z_lo overlay
  // [384,448) U6: bxr -> k (bf16, L0)
  // [448,464)     W_hi/W_lo scratch (dw1T at [448,448.5) pre)
  // [464,472)     t1 (f32, 8MB)
  unsigned short* xxx  = (unsigned short*)(ws + 0 * MB);
  unsigned short* gb   = (unsigned short*)(ws + 0 * MB);     // z_hi
  float*          m5   = (float*)(ws + 64 * MB);
  float*          vf   = (float*)(ws + 64 * MB);             // v f32 [64,192)
  unsigned short* w1T  = (unsigned short*)(ws + 128 * MB);
  unsigned short* bxk  = (unsigned short*)(ws + 128 * MB);
  unsigned short* bxv  = (unsigned short*)(ws + 192 * MB);
  float*          decb = (float*)(ws + 192 * MB);            // dec f32 [192,320)
  unsigned short* bxw  = (unsigned short*)(ws + 256 * MB);
  unsigned short* bxg  = (unsigned short*)(ws + 320 * MB);
  unsigned short* rb   = (unsigned short*)(ws + 320 * MB);   // r, then z_lo overlay
  unsigned short* bxr  = (unsigned short*)(ws + 384 * MB);
  unsigned short* kb   = (unsigned short*)(ws + 384 * MB);   // k bf16 (L0)
  unsigned short* dw1T = (unsigned short*)(ws + 448 * MB);
  unsigned short* Whi  = (unsigned short*)(ws + 448 * MB);
  unsigned short* Wlo  = (unsigned short*)(ws + 456 * MB);
  float*          t1   = (float*)(ws + 464 * MB);
  // optional upgrade: k in f32 at [480,608) if workspace allows (runtime-constant branch)
  const bool kf32 = ws_size >= (size_t)616 * MB;
  float* kf = (float*)(ws + 480 * MB);

  const int nW = A_ * C_;  // 4.19M elements
  const size_t EBT = (size_t)BT_ * C_;

  // 1. token-shift mix -> xxx
  shift_mix<<<(int)(EBT / 4 / 256), 256, 0, stream>>>(x, tmx, xxx);

  // 2. m5 = tanh(xxx @ maa_w1) padded N=256
  transpose_pad<<<(256 * 2048) / 256, 256, 0, stream>>>(w1, w1T, 256, 160);
  gemm_bt<2><<<dim3(BT_ / 128, 2), 256, 0, stream>>>(xxx, w1T, m5, BT_, 256, 2048);

  // 3. five mixed inputs
  mix_lora<<<BT_ / 16, 256, 0, stream>>>(x, m5, w2, tmw, tmk, tmv, tmr, tmg,
                                         bxw, bxk, bxv, bxr, bxg);

  // 4. t1 = tanh(xw @ decay_w1) padded N=128
  transpose_pad<<<(128 * 2048) / 256, 256, 0, stream>>>(dw1, dw1T, 128, 64);
  gemm_bt<2><<<dim3(BT_ / 128, 1), 256, 0, stream>>>(bxw, dw1T, t1, BT_, 128, 2048);

  // 5-8. projections with split-exact weights (order matters for slot recycling)
  conv_hilo<<<nW / 256, 256, 0, stream>>>(Wg, Whi, Wlo, nW);
  gemm_sb<1><<<dim3(BT_ / 128, 16), 256, 0, stream>>>(bxg, Whi, Wlo, gb, BT_, 2048, 2048);
  conv_hilo<<<nW / 256, 256, 0, stream>>>(Wr, Whi, Wlo, nW);
  gemm_sb<0><<<dim3(BT_ / 128, 16), 256, 0, stream>>>(bxr, Whi, Wlo, rb, BT_, 2048, 2048);
  conv_hilo<<<nW / 256, 256, 0, stream>>>(Wk, Whi, Wlo, nW);
  if (kf32) {
    gemm_sb<3><<<dim3(BT_ / 128, 16), 256, 0, stream>>>(bxk, Whi, Wlo, kf, BT_, 2048, 2048);
  } else {
    gemm_sb<0><<<dim3(BT_ / 128, 16), 256, 0, stream>>>(bxk, Whi, Wlo, kb, BT_, 2048, 2048);
  }
  conv_hilo<<<nW / 256, 256, 0, stream>>>(Wv, Whi, Wlo, nW);
  gemm_sb<3><<<dim3(BT_ / 128, 16), 256, 0, stream>>>(bxv, Whi, Wlo, vf, BT_, 2048, 2048);

  // 9. dec (after bxv/bxw are dead; overlays them)
  decay_kernel<<<BT_ / 16, 256, 0, stream>>>(t1, dw2, td, decb);

  // 10. WKV6 scan + fused GroupNorm*g -> z_hi (over g), z_lo (over r)
  if (kf32) {
    wkv6_fused<1><<<256, 256, 0, stream>>>(rb, kb, kf, vf, decb, u, gb, rb, lnw, lnb);
  } else {
    wkv6_fused<0><<<256, 256, 0, stream>>>(rb, kb, kf, vf, decb, u, gb, rb, lnw, lnb);
  }

  // 11. output projection: (z_hi + z_lo) @ (Wo_hi + Wo_lo)^T -> d_out (f32)
  conv_hilo<<<nW / 256, 256, 0, stream>>>(Wo, Whi, Wlo, nW);
  gemm_s3<<<dim3(BT_ / 128, 16), 256, 0, stream>>>(gb, rb, Whi, Wlo, (float*)d_out, BT_, 2048, 2048);
}

// Round 2
// 3283.516 us; speedup vs baseline: 1.7807x; 1.7807x over previous
//
#include <hip/hip_runtime.h>
#include <hip/hip_bf16.h>
#include <cstdint>
#include <cstddef>

#define B_ 8
#define T_ 2048
#define C_ 2048
#define A_ 2048
#define H_ 32
#define BT_ (B_*T_)
#define SEG_ 64

typedef short short8 __attribute__((ext_vector_type(8)));
typedef float floatx4 __attribute__((ext_vector_type(4)));
typedef unsigned short ushortv8 __attribute__((ext_vector_type(8)));

__device__ __forceinline__ unsigned short f2bf(float f) {
  union { float f; uint32_t u; } a; a.f = f;
  uint32_t r = a.u + 0x7fffu + ((a.u >> 16) & 1u);   // RNE
  return (unsigned short)(r >> 16);
}
__device__ __forceinline__ float bf2f(unsigned short s) {
  union { uint32_t u; float f; } a; a.u = ((uint32_t)s) << 16;
  return a.f;
}

// invisible f32 store: keeps __restrict__ load pipelining intact (y rows are
// never re-read inside the scan kernel; a __syncthreads always separates a
// row's last read from its overwrite)
__device__ __forceinline__ void gst_f32(float val, float* addr) {
  asm volatile("global_store_dword %0, %1, off" :: "v"(addr), "v"(val));
}

// ---------------- weight prep: hi/lo bf16 split ----------------
__global__ void conv_hilo(const float* __restrict__ s, unsigned short* __restrict__ hi,
                          unsigned short* __restrict__ lo, int n) {
  int i = blockIdx.x * 256 + threadIdx.x;
  if (i < n) {
    float v = s[i];
    unsigned short h = f2bf(v);
    hi[i] = h;
    lo[i] = f2bf(v - bf2f(h));
  }
}

// src (2048 x NV) f32 -> dst (NP x 2048) bf16, rows >= NV zero-padded
__global__ void transpose_pad(const float* __restrict__ s, unsigned short* __restrict__ d, int NP, int NV) {
  int i = blockIdx.x * 256 + threadIdx.x;  // over NP*2048
  int n = i >> 11, kk = i & 2047;
  if (n < NP) d[i] = (n < NV) ? f2bf(s[kk * NV + n]) : (unsigned short)0;
}

// ---------------- token shift + maa_x mix ----------------
__global__ void shift_mix(const float* __restrict__ x, const float* __restrict__ tmx,
                          unsigned short* __restrict__ xxx) {
  size_t i4 = (size_t)blockIdx.x * 256 + threadIdx.x;   // over BT*C/4
  size_t i = i4 * 4;
  int c = (int)(i & 2047);
  int t = (int)((i >> 11) & 2047);
  float4 xv = *(const float4*)&x[i];
  float4 pv = make_float4(0.f, 0.f, 0.f, 0.f);
  if (t > 0) pv = *(const float4*)&x[i - 2048];
  float4 tv = *(const float4*)&tmx[c];
  ushort4 m;
  m.x = f2bf(xv.x + (pv.x - xv.x) * tv.x);
  m.y = f2bf(xv.y + (pv.y - xv.y) * tv.y);
  m.z = f2bf(xv.z + (pv.z - xv.z) * tv.z);
  m.w = f2bf(xv.w + (pv.w - xv.w) * tv.w);
  *(ushort4*)&xxx[i] = m;
}

// ---------------- async global->LDS helper ----------------
__device__ __forceinline__ void gll16(const void* g, void* l) {
  __builtin_amdgcn_global_load_lds(
      (const __attribute__((address_space(1))) void*)g,
      (__attribute__((address_space(3))) void*)l, 16, 0, 0);
}

// ---------------- plain bf16 GEMM (small-N lora paths): C = A * B^T ----------------
// EPI: 2 = tanh->f32
template<int EPI>
__global__ __launch_bounds__(256)
void gemm_bt(const unsigned short* __restrict__ Am, const unsigned short* __restrict__ Bm,
             void* __restrict__ Cp, int M, int N, int K) {
  __shared__ unsigned short As[128 * 32];
  __shared__ unsigned short Bs[128 * 32];
  const int tid = threadIdx.x;
  const int wid = tid >> 6, lane = tid & 63;
  const int quad = lane >> 4, l15 = lane & 15;
  const long bm = (long)blockIdx.x * 128, bn = (long)blockIdx.y * 128;
  const int wm = (wid & 1) * 64, wn = (wid >> 1) * 64;

  floatx4 acc[4][4];
#pragma unroll
  for (int a = 0; a < 4; a++)
#pragma unroll
    for (int b = 0; b < 4; b++) { floatx4 z = {0.f, 0.f, 0.f, 0.f}; acc[a][b] = z; }

  const int stg_row = wid * 32 + (lane >> 2);
  const int stg_k   = (lane & 3) * 8;
  const int stg_lds = wid * 1024 + lane * 8;

  for (int k0 = 0; k0 < K; k0 += 32) {
    __syncthreads();
#pragma unroll
    for (int p = 0; p < 2; ++p) {
      gll16(Am + (bm + stg_row + p * 16) * (long)K + k0 + stg_k, &As[stg_lds + p * 512]);
      gll16(Bm + (bn + stg_row + p * 16) * (long)K + k0 + stg_k, &Bs[stg_lds + p * 512]);
    }
    __syncthreads();

    short8 af[4], bfr[4];
#pragma unroll
    for (int mi = 0; mi < 4; mi++) af[mi] = *(const short8*)&As[(wm + mi * 16 + l15) * 32 + quad * 8];
#pragma unroll
    for (int ni = 0; ni < 4; ni++) bfr[ni] = *(const short8*)&Bs[(wn + ni * 16 + l15) * 32 + quad * 8];
#pragma unroll
    for (int mi = 0; mi < 4; mi++)
#pragma unroll
      for (int ni = 0; ni < 4; ni++)
        acc[mi][ni] = __builtin_amdgcn_mfma_f32_16x16x32_bf16(af[mi], bfr[ni], acc[mi][ni], 0, 0, 0);
  }

#pragma unroll
  for (int mi = 0; mi < 4; mi++)
#pragma unroll
    for (int ni = 0; ni < 4; ni++)
#pragma unroll
      for (int vv = 0; vv < 4; ++vv) {
        long row = bm + wm + mi * 16 + quad * 4 + vv;
        long col = bn + wn + ni * 16 + l15;
        float val = acc[mi][ni][vv];
        if (EPI == 2) ((float*)Cp)[row * N + col] = tanhf(val);
      }
}

// ---------------- split-B GEMM: C = A * (Bh+Bl)^T  (weight-exact) ----------------
// EPI: 0 = ->bf16, 1 = silu->bf16, 3 = ->f32
template<int EPI>
__global__ __launch_bounds__(256)
void gemm_sb(const unsigned short* __restrict__ Am, const unsigned short* __restrict__ Bhm,
             const unsigned short* __restrict__ Blm, void* __restrict__ Cp, int M, int N, int K) {
  __shared__ unsigned short As[128 * 32];
  __shared__ unsigned short Bhs[128 * 32];
  __shared__ unsigned short Bls[128 * 32];
  const int tid = threadIdx.x;
  const int wid = tid >> 6, lane = tid & 63;
  const int quad = lane >> 4, l15 = lane & 15;
  const long bm = (long)blockIdx.x * 128, bn = (long)blockIdx.y * 128;
  const int wm = (wid & 1) * 64, wn = (wid >> 1) * 64;

  floatx4 acc[4][4];
#pragma unroll
  for (int a = 0; a < 4; a++)
#pragma unroll
    for (int b = 0; b < 4; b++) { floatx4 z = {0.f, 0.f, 0.f, 0.f}; acc[a][b] = z; }

  const int stg_row = wid * 32 + (lane >> 2);
  const int stg_k   = (lane & 3) * 8;
  const int stg_lds = wid * 1024 + lane * 8;

  for (int k0 = 0; k0 < K; k0 += 32) {
    __syncthreads();
#pragma unroll
    for (int p = 0; p < 2; ++p) {
      const long rowA = (bm + stg_row + p * 16) * (long)K + k0 + stg_k;
      const long rowB = (bn + stg_row + p * 16) * (long)K + k0 + stg_k;
      gll16(Am  + rowA, &As [stg_lds + p * 512]);
      gll16(Bhm + rowB, &Bhs[stg_lds + p * 512]);
      gll16(Blm + rowB, &Bls[stg_lds + p * 512]);
    }
    __syncthreads();

    short8 af[4], bh[4], bl[4];
#pragma unroll
    for (int mi = 0; mi < 4; mi++) af[mi] = *(const short8*)&As[(wm + mi * 16 + l15) * 32 + quad * 8];
#pragma unroll
    for (int ni = 0; ni < 4; ni++) {
      bh[ni] = *(const short8*)&Bhs[(wn + ni * 16 + l15) * 32 + quad * 8];
      bl[ni] = *(const short8*)&Bls[(wn + ni * 16 + l15) * 32 + quad * 8];
    }
#pragma unroll
    for (int mi = 0; mi < 4; mi++)
#pragma unroll
      for (int ni = 0; ni < 4; ni++) {
        acc[mi][ni] = __builtin_amdgcn_mfma_f32_16x16x32_bf16(af[mi], bh[ni], acc[mi][ni], 0, 0, 0);
        acc[mi][ni] = __builtin_amdgcn_mfma_f32_16x16x32_bf16(af[mi], bl[ni], acc[mi][ni], 0, 0, 0);
      }
  }

#pragma unroll
  for (int mi = 0; mi < 4; mi++)
#pragma unroll
    for (int ni = 0; ni < 4; ni++)
#pragma unroll
      for (int vv = 0; vv < 4; ++vv) {
        long row = bm + wm + mi * 16 + quad * 4 + vv;
        long col = bn + wn + ni * 16 + l15;
        float val = acc[mi][ni][vv];
        if (EPI == 0) {
          ((unsigned short*)Cp)[row * N + col] = f2bf(val);
        } else if (EPI == 1) {
          float s = val / (1.f + __expf(-val));
          ((unsigned short*)Cp)[row * N + col] = f2bf(s);
        } else {
          ((float*)Cp)[row * N + col] = val;
        }
      }
}

// ---------------- 3-term GEMM: C = Ah*Bh^T + Ah*Bl^T + Al*Bh^T -> f32 (final proj) ----------------
__global__ __launch_bounds__(256)
void gemm_s3(const unsigned short* __restrict__ Ahm, const unsigned short* __restrict__ Alm,
             const unsigned short* __restrict__ Bhm, const unsigned short* __restrict__ Blm,
             float* __restrict__ Cp, int M, int N, int K) {
  __shared__ unsigned short Ahs[128 * 32];
  __shared__ unsigned short Als[128 * 32];
  __shared__ unsigned short Bhs[128 * 32];
  __shared__ unsigned short Bls[128 * 32];
  const int tid = threadIdx.x;
  const int wid = tid >> 6, lane = tid & 63;
  const int quad = lane >> 4, l15 = lane & 15;
  const long bm = (long)blockIdx.x * 128, bn = (long)blockIdx.y * 128;
  const int wm = (wid & 1) * 64, wn = (wid >> 1) * 64;

  floatx4 acc[4][4];
#pragma unroll
  for (int a = 0; a < 4; a++)
#pragma unroll
    for (int b = 0; b < 4; b++) { floatx4 z = {0.f, 0.f, 0.f, 0.f}; acc[a][b] = z; }

  const int stg_row = wid * 32 + (lane >> 2);
  const int stg_k   = (lane & 3) * 8;
  const int stg_lds = wid * 1024 + lane * 8;

  for (int k0 = 0; k0 < K; k0 += 32) {
    __syncthreads();
#pragma unroll
    for (int p = 0; p < 2; ++p) {
      const long rowA = (bm + stg_row + p * 16) * (long)K + k0 + stg_k;
      const long rowB = (bn + stg_row + p * 16) * (long)K + k0 + stg_k;
      gll16(Ahm + rowA, &Ahs[stg_lds + p * 512]);
      gll16(Alm + rowA, &Als[stg_lds + p * 512]);
      gll16(Bhm + rowB, &Bhs[stg_lds + p * 512]);
      gll16(Blm + rowB, &Bls[stg_lds + p * 512]);
    }
    __syncthreads();

    short8 ah[4], al[4], bh[4], bl[4];
#pragma unroll
    for (int mi = 0; mi < 4; mi++) {
      ah[mi] = *(const short8*)&Ahs[(wm + mi * 16 + l15) * 32 + quad * 8];
      al[mi] = *(const short8*)&Als[(wm + mi * 16 + l15) * 32 + quad * 8];
    }
#pragma unroll
    for (int ni = 0; ni < 4; ni++) {
      bh[ni] = *(const short8*)&Bhs[(wn + ni * 16 + l15) * 32 + quad * 8];
      bl[ni] = *(const short8*)&Bls[(wn + ni * 16 + l15) * 32 + quad * 8];
    }
#pragma unroll
    for (int mi = 0; mi < 4; mi++)
#pragma unroll
      for (int ni = 0; ni < 4; ni++) {
        acc[mi][ni] = __builtin_amdgcn_mfma_f32_16x16x32_bf16(ah[mi], bh[ni], acc[mi][ni], 0, 0, 0);
        acc[mi][ni] = __builtin_amdgcn_mfma_f32_16x16x32_bf16(ah[mi], bl[ni], acc[mi][ni], 0, 0, 0);
        acc[mi][ni] = __builtin_amdgcn_mfma_f32_16x16x32_bf16(al[mi], bh[ni], acc[mi][ni], 0, 0, 0);
      }
  }

#pragma unroll
  for (int mi = 0; mi < 4; mi++)
#pragma unroll
    for (int ni = 0; ni < 4; ni++)
#pragma unroll
      for (int vv = 0; vv < 4; ++vv) {
        long row = bm + wm + mi * 16 + quad * 4 + vv;
        long col = bn + wn + ni * 16 + l15;
        Cp[row * N + col] = acc[mi][ni][vv];
      }
}

// ---------------- fused LoRA-mix (xx recomputed inline) ----------------
__global__ __launch_bounds__(256)
void mix_lora(const float* __restrict__ x,
              const float* __restrict__ m5, const float* __restrict__ w2,
              const float* __restrict__ tmw, const float* __restrict__ tmk,
              const float* __restrict__ tmv, const float* __restrict__ tmr,
              const float* __restrict__ tmg,
              unsigned short* __restrict__ xw, unsigned short* __restrict__ xk,
              unsigned short* __restrict__ xv, unsigned short* __restrict__ xr,
              unsigned short* __restrict__ xg) {
  const int bt0 = blockIdx.x * 16;
  const int tid = threadIdx.x;
  const float* tms[5] = {tmw, tmk, tmv, tmr, tmg};
  unsigned short* outs[5] = {xw, xk, xv, xr, xg};
  for (int cc = 0; cc < 8; ++cc) {
    const int c = cc * 256 + tid;
    float xv_[16], xxv_[16];
#pragma unroll
    for (int b = 0; b < 16; b++) {
      const int bt = bt0 + b;
      size_t idx = ((size_t)bt << 11) + c;
      float xc = x[idx];
      float xp = ((bt & 2047) > 0) ? x[idx - 2048] : 0.f;
      xv_[b] = xc; xxv_[b] = xp - xc;
    }
#pragma unroll
    for (int f = 0; f < 5; ++f) {
      const float tmf = tms[f][c];
      float acc[16];
#pragma unroll
      for (int b = 0; b < 16; b++) acc[b] = 0.f;
      for (int dc = 0; dc < 8; ++dc) {
        float wv0 = w2[((size_t)(f * 32 + dc * 4 + 0) << 11) + c];
        float wv1 = w2[((size_t)(f * 32 + dc * 4 + 1) << 11) + c];
        float wv2 = w2[((size_t)(f * 32 + dc * 4 + 2) << 11) + c];
        float wv3 = w2[((size_t)(f * 32 + dc * 4 + 3) << 11) + c];
#pragma unroll
        for (int b = 0; b < 16; b++) {
          float4 mv = *(const float4*)&m5[((size_t)(bt0 + b) << 8) + f * 32 + dc * 4];
          acc[b] += mv.x * wv0 + mv.y * wv1 + mv.z * wv2 + mv.w * wv3;
        }
      }
#pragma unroll
      for (int b = 0; b < 16; b++) {
        size_t idx = ((size_t)(bt0 + b) << 11) + c;
        outs[f][idx] = f2bf(xv_[b] + xxv_[b] * (tmf + acc[b]));
      }
    }
  }
}

// ---------------- decay: dec = exp(-exp(td + t1 @ decay_w2)) (f32) ----------------
__global__ __launch_bounds__(256)
void decay_kernel(const float* __restrict__ t1, const float* __restrict__ w2d,
                  const float* __restrict__ td, float* __restrict__ dec) {
  const int bt0 = blockIdx.x * 16;
  const int tid = threadIdx.x;
  for (int cc = 0; cc < 8; ++cc) {
    const int a = cc * 256 + tid;
    const float tda = td[a];
    float acc[16];
#pragma unroll
    for (int b = 0; b < 16; b++) acc[b] = 0.f;
    for (int dc = 0; dc < 16; ++dc) {
      float wv0 = w2d[((size_t)(dc * 4 + 0) << 11) + a];
      float wv1 = w2d[((size_t)(dc * 4 + 1) << 11) + a];
      float wv2 = w2d[((size_t)(dc * 4 + 2) << 11) + a];
      float wv3 = w2d[((size_t)(dc * 4 + 3) << 11) + a];
#pragma unroll
      for (int b = 0; b < 16; b++) {
        float4 mv = *(const float4*)&t1[((size_t)(bt0 + b) << 7) + dc * 4];
        acc[b] += mv.x * wv0 + mv.y * wv1 + mv.z * wv2 + mv.w * wv3;
      }
    }
#pragma unroll
    for (int b = 0; b < 16; b++) {
      dec[((size_t)(bt0 + b) << 11) + a] = __expf(-__expf(tda + acc[b]));
    }
  }
}

// ---------------- WKV6 scan, barrier-free j-split ----------------
// block = one (b,h), 512 threads = 8 waves. Wave w owns value-columns
// [8w,8w+8) of the head; lane: g = lane>>3 (i-group of 8 key-channels),
// jl = lane&7 (column). S[8] per lane covers (8 i) x (1 col); block total
// = 64x64 state, no duplication. i-reduction = 3 intra-wave shfl_xor.
// No per-step barriers: y[t] written (invisible asm store) to dec row t-SEG
// (dead after read) / scratch ybuf0 for t<SEG. One __syncthreads per SEG
// steps bounds wave skew so reads of a dec row always precede its overwrite.
// 4-deep register prefetch (rows t..t+3 in flight).
template<int KF32>
__global__ __launch_bounds__(512, 1)
void wkv6_scan(const unsigned short* __restrict__ r, const unsigned short* __restrict__ k16,
               const float* __restrict__ k32, const float* __restrict__ v,
               const float* __restrict__ dec, const float* __restrict__ u,
               float* __restrict__ ybuf0, float* ydec) {
  const int bh = blockIdx.x;
  const int b = bh >> 5, h = bh & 31;
  const int tid = threadIdx.x;
  const int w = tid >> 6, lane = tid & 63;
  const int g = lane >> 3, jl = lane & 7;
  const int ci = g * 8;            // i-offset of this lane's key-channel group
  const int j = w * 8 + jl;        // value-column within head
  const int cj = h * 64 + j;

  float S[8];
#pragma unroll
  for (int m = 0; m < 8; ++m) S[m] = 0.f;
  float uu[8];
#pragma unroll
  for (int m = 0; m < 8; ++m) uu[m] = u[h * 64 + ci + m];

  const size_t base = ((size_t)b * T_) * (size_t)A_ + h * 64;
  float* yb0 = ybuf0 + ((size_t)b * SEG_) * (size_t)A_ + cj;
  float* ydb = ydec + ((ptrdiff_t)b * T_ - SEG_) * (ptrdiff_t)A_ + cj;

#define DECL_BUF(N) ushortv8 rv##N; ushortv8 kh##N; float4 ka##N, kb##N, da##N, db##N; float vv##N;
#define LOAD_BUF(N, TI) do {                                                    \
    const size_t o_ = base + (size_t)(TI) * A_;                                 \
    rv##N = *(const ushortv8*)&r[o_ + ci];                                      \
    if (KF32) { ka##N = *(const float4*)&k32[o_ + ci];                          \
                kb##N = *(const float4*)&k32[o_ + ci + 4]; }                    \
    else      { kh##N = *(const ushortv8*)&k16[o_ + ci]; }                      \
    da##N = *(const float4*)&dec[o_ + ci];                                      \
    db##N = *(const float4*)&dec[o_ + ci + 4];                                  \
    vv##N = v[o_ + j];                                                          \
  } while (0)
#define COMP_BUF(N, TI) do {                                                    \
    float rr_[8], kk_[8], dd_[8];                                               \
    _Pragma("unroll")                                                           \
    for (int m = 0; m < 4; ++m) {                                               \
      rr_[m]     = bf2f(rv##N[m]);                                              \
      rr_[m + 4] = bf2f(rv##N[m + 4]);                                          \
      dd_[m]     = da##N[m];                                                    \
      dd_[m + 4] = db##N[m];                                                    \
      if (KF32) { kk_[m] = ka##N[m]; kk_[m + 4] = kb##N[m]; }                   \
      else      { kk_[m] = bf2f(kh##N[m]); kk_[m + 4] = bf2f(kh##N[m + 4]); }   \
    }                                                                           \
    float y_ = 0.f;                                                             \
    _Pragma("unroll")                                                           \
    for (int m = 0; m < 8; ++m) {                                               \
      float kv = kk_[m] * vv##N;                                                \
      y_ = fmaf(rr_[m], fmaf(uu[m], kv, S[m]), y_);                             \
      S[m] = fmaf(dd_[m], S[m], kv);                                            \
    }                                                                           \
    y_ += __shfl_xor(y_, 8, 64);                                                \
    y_ += __shfl_xor(y_, 16, 64);                                               \
    y_ += __shfl_xor(y_, 32, 64);                                               \
    if (g == 0) {                                                               \
      float* yo_ = (((TI) < SEG_) ? yb0 : ydb) + (size_t)(TI) * A_;             \
      gst_f32(y_, yo_);                                                         \
    }                                                                           \
  } while (0)

  DECL_BUF(0) DECL_BUF(1) DECL_BUF(2) DECL_BUF(3)
  LOAD_BUF(0, 0); LOAD_BUF(1, 1); LOAD_BUF(2, 2); LOAD_BUF(3, 3);

  for (int s = 0; s < T_ / SEG_; ++s) {
    if (s) __syncthreads();   // bounds wave skew: reads of a row precede its y-overwrite
    const int t0 = s * SEG_;
    for (int tt = 0; tt < SEG_; tt += 4) {
      const int t = t0 + tt;
      const int n0 = (t + 4 < T_) ? t + 4 : T_ - 1;
      const int n1 = (t + 5 < T_) ? t + 5 : T_ - 1;
      const int n2 = (t + 6 < T_) ? t + 6 : T_ - 1;
      const int n3 = (t + 7 < T_) ? t + 7 : T_ - 1;
      COMP_BUF(0, t);     LOAD_BUF(0, n0);
      COMP_BUF(1, t + 1); LOAD_BUF(1, n1);
      COMP_BUF(2, t + 2); LOAD_BUF(2, n2);
      COMP_BUF(3, t + 3); LOAD_BUF(3, n3);
    }
  }
  asm volatile("s_waitcnt vmcnt(0)" ::: "memory");   // drain invisible stores
#undef DECL_BUF
#undef LOAD_BUF
#undef COMP_BUF
}

// ---------------- GroupNorm*g epilogue: z = GN(y)*g -> z_hi (over g), z_lo (over r) ----------------
__global__ __launch_bounds__(256)
void gn_fuse(const float* __restrict__ ydec, const float* __restrict__ ybuf0,
             unsigned short* __restrict__ gz, unsigned short* __restrict__ zlo,
             const float* __restrict__ lnw, const float* __restrict__ lnb) {
  const int bt = blockIdx.x;
  const int t = bt & (T_ - 1), b = bt >> 11;
  const int w = threadIdx.x >> 6, j = threadIdx.x & 63;
  const float* ys = (t < SEG_) ? (ybuf0 + ((size_t)b * SEG_ + t) * (size_t)A_)
                               : (ydec + ((size_t)bt - SEG_) * (size_t)A_);
  const size_t rowo = (size_t)bt * (size_t)A_;
#pragma unroll
  for (int hh = 0; hh < 8; ++hh) {
    const int h = hh * 4 + w;
    const int c = h * 64 + j;
    float yj = ys[c];
    float sm = yj, sq = yj * yj;
#pragma unroll
    for (int d = 32; d > 0; d >>= 1) {
      sm += __shfl_xor(sm, d, 64);
      sq += __shfl_xor(sq, d, 64);
    }
    float mu = sm * (1.f / 64.f);
    float var = sq * (1.f / 64.f) - mu * mu;
    float rs = rsqrtf(var + 6.4e-4f);   // EPS = 1e-5 * 64
    float yn = (yj - mu) * rs * lnw[c] + lnb[c];
    float z = yn * bf2f(gz[rowo + c]);
    unsigned short zh = f2bf(z);
    gz[rowo + c] = zh;
    zlo[rowo + c] = f2bf(z - bf2f(zh));
  }
}

// ---------------- launch ----------------
extern "C" void kernel_launch(void* const* d_in, const int* in_sizes, int n_in,
                              void* d_out, int out_size, void* d_ws, size_t ws_size,
                              hipStream_t stream) {
  (void)in_sizes; (void)n_in; (void)out_size;
  const float* x   = (const float*)d_in[0];
  const float* tmx = (const float*)d_in[1];
  const float* tmw = (const float*)d_in[2];
  const float* tmk = (const float*)d_in[3];
  const float* tmv = (const float*)d_in[4];
  const float* tmr = (const float*)d_in[5];
  const float* tmg = (const float*)d_in[6];
  const float* w1  = (const float*)d_in[7];   // (C,160)
  const float* w2  = (const float*)d_in[8];   // (5,32,C)
  const float* td  = (const float*)d_in[9];   // (A)
  const float* dw1 = (const float*)d_in[10];  // (C,64)
  const float* dw2 = (const float*)d_in[11];  // (64,A)
  const float* u   = (const float*)d_in[12];  // (H,N)
  const float* Wr  = (const float*)d_in[13];
  const float* Wk  = (const float*)d_in[14];
  const float* Wv  = (const float*)d_in[15];
  const float* Wg  = (const float*)d_in[16];
  const float* Wo  = (const float*)d_in[17];
  const float* lnw = (const float*)d_in[18];
  const float* lnb = (const float*)d_in[19];

  char* ws = (char*)d_ws;
  const size_t MB = 1024 * 1024;
  // 472MB layout (proven safe footprint), lifetime-overlapped:
  // [0,64)    U0: xxx -> g -> z_hi (in place)
  // [64,80)       m5 (f32, 16MB) -> later v-f32 lower half spans [64,128)
  // [128,192) U2: bxk (w1T scratch at [128,129) pre-mix) -> v-f32 upper half
  // [192,256) U3: bxv -> dec lower half
  // [256,320) U4: bxw -> dec upper half     (dec = [192,320) f32; y overlays dec rows t-SEG)
  // [320,384) U5: bxg -> r -> z_lo overlay (gn kernel)
  // [384,448) U6: bxr -> k (bf16, L0)
  // [448,464)     W_hi/W_lo scratch (dw1T pre) -> ybuf0 (4MB, scan) -> W_hi/W_lo (Wo)
  // [464,472)     t1 (f32, 8MB)
  unsigned short* xxx  = (unsigned short*)(ws + 0 * MB);
  unsigned short* gb   = (unsigned short*)(ws + 0 * MB);     // z_hi
  float*          m5   = (float*)(ws + 64 * MB);
  float*          vf   = (float*)(ws + 64 * MB);             // v f32 [64,192)
  unsigned short* w1T  = (unsigned short*)(ws + 128 * MB);
  unsigned short* bxk  = (unsigned short*)(ws + 128 * MB);
  unsigned short* bxv  = (unsigned short*)(ws + 192 * MB);
  float*          decb = (float*)(ws + 192 * MB);            // dec f32 [192,320)
  unsigned short* bxw  = (unsigned short*)(ws + 256 * MB);
  unsigned short* bxg  = (unsigned short*)(ws + 320 * MB);
  unsigned short* rb   = (unsigned short*)(ws + 320 * MB);   // r, then z_lo overlay
  unsigned short* bxr  = (unsigned short*)(ws + 384 * MB);
  unsigned short* kb   = (unsigned short*)(ws + 384 * MB);   // k bf16 (L0)
  unsigned short* dw1T = (unsigned short*)(ws + 448 * MB);
  unsigned short* Whi  = (unsigned short*)(ws + 448 * MB);
  unsigned short* Wlo  = (unsigned short*)(ws + 456 * MB);
  float*          ybuf0= (float*)(ws + 448 * MB);            // 4MB, scan-time only
  float*          t1   = (float*)(ws + 464 * MB);
  // optional upgrade: k in f32 at [480,608) if workspace allows (runtime-constant branch)
  const bool kf32 = ws_size >= (size_t)616 * MB;
  float* kf = (float*)(ws + 480 * MB);

  const int nW = A_ * C_;  // 4.19M elements
  const size_t EBT = (size_t)BT_ * C_;

  // 1. token-shift mix -> xxx
  shift_mix<<<(int)(EBT / 4 / 256), 256, 0, stream>>>(x, tmx, xxx);

  // 2. m5 = tanh(xxx @ maa_w1) padded N=256
  transpose_pad<<<(256 * 2048) / 256, 256, 0, stream>>>(w1, w1T, 256, 160);
  gemm_bt<2><<<dim3(BT_ / 128, 2), 256, 0, stream>>>(xxx, w1T, m5, BT_, 256, 2048);

  // 3. five mixed inputs
  mix_lora<<<BT_ / 16, 256, 0, stream>>>(x, m5, w2, tmw, tmk, tmv, tmr, tmg,
                                         bxw, bxk, bxv, bxr, bxg);

  // 4. t1 = tanh(xw @ decay_w1) padded N=128
  transpose_pad<<<(128 * 2048) / 256, 256, 0, stream>>>(dw1, dw1T, 128, 64);
  gemm_bt<2><<<dim3(BT_ / 128, 1), 256, 0, stream>>>(bxw, dw1T, t1, BT_, 128, 2048);

  // 5-8. projections with split-exact weights (order matters for slot recycling)
  conv_hilo<<<nW / 256, 256, 0, stream>>>(Wg, Whi, Wlo, nW);
  gemm_sb<1><<<dim3(BT_ / 128, 16), 256, 0, stream>>>(bxg, Whi, Wlo, gb, BT_, 2048, 2048);
  conv_hilo<<<nW / 256, 256, 0, stream>>>(Wr, Whi, Wlo, nW);
  gemm_sb<0><<<dim3(BT_ / 128, 16), 256, 0, stream>>>(bxr, Whi, Wlo, rb, BT_, 2048, 2048);
  conv_hilo<<<nW / 256, 256, 0, stream>>>(Wk, Whi, Wlo, nW);
  if (kf32) {
    gemm_sb<3><<<dim3(BT_ / 128, 16), 256, 0, stream>>>(bxk, Whi, Wlo, kf, BT_, 2048, 2048);
  } else {
    gemm_sb<0><<<dim3(BT_ / 128, 16), 256, 0, stream>>>(bxk, Whi, Wlo, kb, BT_, 2048, 2048);
  }
  conv_hilo<<<nW / 256, 256, 0, stream>>>(Wv, Whi, Wlo, nW);
  gemm_sb<3><<<dim3(BT_ / 128, 16), 256, 0, stream>>>(bxv, Whi, Wlo, vf, BT_, 2048, 2048);

  // 9. dec (after bxv/bxw are dead; overlays them)
  decay_kernel<<<BT_ / 16, 256, 0, stream>>>(t1, dw2, td, decb);

  // 10. WKV6 scan (barrier-free): y -> dec-row overlay + ybuf0 for t<SEG
  if (kf32) {
    wkv6_scan<1><<<256, 512, 0, stream>>>(rb, kb, kf, vf, decb, u, ybuf0, decb);
  } else {
    wkv6_scan<0><<<256, 512, 0, stream>>>(rb, kb, kf, vf, decb, u, ybuf0, decb);
  }

  // 10b. GroupNorm*g epilogue -> z_hi (over g), z_lo (over r)
  gn_fuse<<<BT_, 256, 0, stream>>>(decb, ybuf0, gb, rb, lnw, lnb);

  // 11. output projection: (z_hi + z_lo) @ (Wo_hi + Wo_lo)^T -> d_out (f32)
  conv_hilo<<<nW / 256, 256, 0, stream>>>(Wo, Whi, Wlo, nW);
  gemm_s3<<<dim3(BT_ / 128, 16), 256, 0, stream>>>(gb, rb, Whi, Wlo, (float*)d_out, BT_, 2048, 2048);
}